// Round 2
// baseline (392.103 us; speedup 1.0000x reference)
//
#include <hip/hip_runtime.h>
#include <math.h>

#define HBINS  4096
#define CAP    4096
#define MAXDET 100
#define NTHR   256
// Static prefilter threshold on raw scores. For the benched input
// (4.19M iid N(0,1)) E[count raw>3.5] ~ 975 (sigma ~31): safely inside
// [MAXDET, CAP]. Any input where that fails takes the exact single-block
// fallback path in k_finalize (correct for arbitrary data, just slower).
#define RAW_T0 3.5f

// Order-preserving float -> uint key (larger float => larger key).
static __device__ __forceinline__ unsigned f2key(float f) {
    unsigned u = __float_as_uint(f);
    return (u & 0x80000000u) ? ~u : (u | 0x80000000u);
}

// Single pass: compact (score, index) of all elements with raw > RAW_T0.
// If the resulting count is in [MAXDET, CAP], the true top-100 is provably
// a subset of the candidates (the 100th-best raw is > RAW_T0).
__global__ __launch_bounds__(NTHR) void k_compact_static(
    const float4* __restrict__ s4, int n4,
    unsigned* __restrict__ counter,
    float* __restrict__ cs, unsigned* __restrict__ ci) {
    int stride = gridDim.x * NTHR;
    for (int i = blockIdx.x * NTHR + threadIdx.x; i < n4; i += stride) {
        float4 v = s4[i];
        float f[4] = {v.x, v.y, v.z, v.w};
#pragma unroll
        for (int c = 0; c < 4; ++c) {
            if (f[c] > RAW_T0) {
                unsigned p = atomicAdd(counter, 1u);
                if (p < CAP) { cs[p] = f[c]; ci[p] = (unsigned)i * 4u + (unsigned)c; }
            }
        }
    }
}

// Select top-100 in order (bitonic sort), decode boxes, bitmask greedy NMS,
// conf filter, write (100,5). Contains a single-block exact fallback
// (histogram + threshold + recompact) for inputs where the static prefilter
// under/over-shoots.
__global__ __launch_bounds__(NTHR) void k_finalize(
    const float* __restrict__ rb, const float* __restrict__ an,
    const float4* __restrict__ s4, int n4,
    float* __restrict__ cs, unsigned* __restrict__ ci,
    const unsigned* __restrict__ counter,
    float* __restrict__ out) {
    __shared__ unsigned long long comp[CAP];   // 32 KB; aliased as hist in fallback
    __shared__ unsigned buf0[NTHR], buf1[NTHR];
    __shared__ unsigned s_tk, s_cnt;
    __shared__ float bx[MAXDET][4];
    __shared__ float ssc[MAXDET];
    __shared__ unsigned long long suppLo[MAXDET];
    __shared__ unsigned long long suppHi[MAXDET];
    __shared__ unsigned long long keepOut[2];

    int t = threadIdx.x;
    unsigned n = *counter;

    if (n < MAXDET || n > CAP) {
        // ---- Exact fallback (pathological inputs only): single-block
        // histogram -> suffix-scan threshold -> recompact. ----
        unsigned* h = (unsigned*)comp;         // 16 KB alias, dead before sort
        for (int i = t; i < HBINS; i += NTHR) h[i] = 0u;
        __syncthreads();
        for (int i = t; i < n4; i += NTHR) {
            float4 v = s4[i];
            atomicAdd(&h[f2key(v.x) >> 20], 1u);
            atomicAdd(&h[f2key(v.y) >> 20], 1u);
            atomicAdd(&h[f2key(v.z) >> 20], 1u);
            atomicAdd(&h[f2key(v.w) >> 20], 1u);
        }
        __syncthreads();
        unsigned loc[16];
        unsigned s = 0;
#pragma unroll
        for (int i = 0; i < 16; ++i) { loc[i] = h[t * 16 + i]; s += loc[i]; }
        buf0[t] = s;
        __syncthreads();
        unsigned* src = buf0; unsigned* dst = buf1;
        for (int off = 1; off < NTHR; off <<= 1) {   // inclusive suffix scan
            unsigned v = src[t];
            if (t + off < NTHR) v += src[t + off];
            __syncthreads();
            dst[t] = v;
            __syncthreads();
            unsigned* tmp = src; src = dst; dst = tmp;
        }
        unsigned after = (t + 1 < NTHR) ? src[t + 1] : 0u;
        if (after < MAXDET && after + s >= MAXDET) {
            unsigned run = after;
#pragma unroll
            for (int i = 15; i >= 0; --i) {
                run += loc[i];
                if (run >= MAXDET) { s_tk = ((unsigned)(t * 16 + i)) << 20; break; }
            }
        }
        if (t == 0 && src[0] < MAXDET) s_tk = 0u;   // fewer than 100 total
        if (t == 0) s_cnt = 0u;
        __syncthreads();
        unsigned tk = s_tk;
        for (int i = t; i < n4; i += NTHR) {
            float4 v = s4[i];
            float f[4] = {v.x, v.y, v.z, v.w};
#pragma unroll
            for (int c = 0; c < 4; ++c) {
                if (f2key(f[c]) >= tk) {
                    unsigned p = atomicAdd(&s_cnt, 1u);
                    if (p < CAP) { cs[p] = f[c]; ci[p] = (unsigned)i * 4u + (unsigned)c; }
                }
            }
        }
        __syncthreads();
        n = s_cnt;
        if (n > CAP) n = CAP;
        __syncthreads();
    }

    // Composite keys: (score key << 32) | (~idx) => max = best score, tie: lowest idx.
    // Encodes jax.lax.top_k ordering exactly, so descending sort == selection order.
    for (unsigned i = (unsigned)t; i < n; i += NTHR) {
        comp[i] = ((unsigned long long)f2key(cs[i]) << 32) |
                  (unsigned long long)(0xFFFFFFFFu - ci[i]);
    }
    unsigned P = 128;
    while (P < n) P <<= 1;
    for (unsigned i = n + (unsigned)t; i < P; i += NTHR) comp[i] = 0ull;
    __syncthreads();

    // Bitonic sort, descending. P in [128, 4096]; typical n~1000 -> P=1024.
    for (unsigned k = 2; k <= P; k <<= 1) {
        for (unsigned j = k >> 1; j > 0; j >>= 1) {
            for (unsigned i = (unsigned)t; i < P; i += NTHR) {
                unsigned l = i ^ j;
                if (l > i) {
                    unsigned long long a = comp[i], b = comp[l];
                    bool up = ((i & k) == 0);          // descending network
                    if (up ? (a < b) : (a > b)) { comp[i] = b; comp[l] = a; }
                }
            }
            __syncthreads();
        }
    }

    // Decode the 100 selected boxes (reference math, fp32) + init supp masks.
    if (t < MAXDET) {
        unsigned long long gb = comp[t];
        float raw;
        unsigned id;
        if (gb == 0ull) {                 // fewer than 100 candidates (pathological)
            raw = -3.0e38f;
            id = 0u;
        } else {
            unsigned key = (unsigned)(gb >> 32);
            unsigned u = (key & 0x80000000u) ? (key & 0x7FFFFFFFu) : ~key;
            raw = __uint_as_float(u);
            id = 0xFFFFFFFFu - (unsigned)(gb & 0xFFFFFFFFull);
        }
        size_t b = (size_t)id * 16;
        float rb0 = rb[b + 0], rb1 = rb[b + 1], rb2 = rb[b + 2], rb3 = rb[b + 3];
        size_t a = (size_t)id * 4;
        float ax = an[a + 0], ay = an[a + 1], aw = an[a + 2], ah = an[a + 3];
        const float inv = 1.0f / 128.0f;   // INPUT_SIZE, exact power of two
        float xc = rb0 * inv * aw + ax;
        float yc = rb1 * inv * ah + ay;
        float w  = rb2 * inv * aw;
        float h  = rb3 * inv * ah;
        float y0 = yc - h * 0.5f, y1 = yc + h * 0.5f;
        float x0 = xc - w * 0.5f, x1 = xc + w * 0.5f;
        bx[t][0] = fminf(y0, y1);
        bx[t][1] = fminf(x0, x1);
        bx[t][2] = fmaxf(y0, y1);
        bx[t][3] = fmaxf(x0, x1);
        float r = fminf(fmaxf(raw, -100.0f), 100.0f);
        ssc[t] = 1.0f / (1.0f + expf(-r));
        suppLo[t] = 0ull;
        suppHi[t] = 0ull;
    }
    __syncthreads();

    // Parallel IoU: all (i,j) j>i pairs -> suppression bitmasks (bit j of supp[i]).
    for (int p = t; p < MAXDET * MAXDET; p += NTHR) {
        int i = p / MAXDET, j = p - i * MAXDET;
        if (j > i) {
            float x1i = bx[i][1], y1i = bx[i][0], x2i = bx[i][3], y2i = bx[i][2];
            float x1j = bx[j][1], y1j = bx[j][0], x2j = bx[j][3], y2j = bx[j][2];
            float areai = (x2i - x1i) * (y2i - y1i);
            float areaj = (x2j - x1j) * (y2j - y1j);
            float xx1 = fmaxf(x1i, x1j), yy1 = fmaxf(y1i, y1j);
            float xx2 = fminf(x2i, x2j), yy2 = fminf(y2i, y2j);
            float iw = fmaxf(xx2 - xx1, 0.0f), ih = fmaxf(yy2 - yy1, 0.0f);
            float inter = iw * ih;
            float uni = areai + areaj - inter;
            float iou = inter / fmaxf(uni, 1e-9f);
            if (iou > 0.3f) {
                if (j < 64) atomicOr(&suppLo[i], 1ull << j);
                else        atomicOr(&suppHi[i], 1ull << (j - 64));
            }
        }
    }
    __syncthreads();

    // Sequential greedy resolve on register-resident masks (wave 0, all lanes uniform).
    // Exactly the reference fori_loop: supp applied only if i still kept at time i.
    if (t < 64) {
        unsigned long long a0 = suppLo[t], a1 = suppHi[t];
        unsigned long long b0 = (t < MAXDET - 64) ? suppLo[64 + t] : 0ull;
        unsigned long long b1 = (t < MAXDET - 64) ? suppHi[64 + t] : 0ull;
        unsigned long long kLo = ~0ull;
        unsigned long long kHi = (1ull << (MAXDET - 64)) - 1;
        for (int i = 0; i < MAXDET - 1; ++i) {
            bool kept = (i < 64) ? ((kLo >> i) & 1ull) : ((kHi >> (i - 64)) & 1ull);
            if (kept) {                                  // uniform across lanes
                unsigned long long mLo = (i < 64) ? __shfl(a0, i) : __shfl(b0, i - 64);
                unsigned long long mHi = (i < 64) ? __shfl(a1, i) : __shfl(b1, i - 64);
                kLo &= ~mLo;
                kHi &= ~mHi;
            }
        }
        if (t == 0) { keepOut[0] = kLo; keepOut[1] = kHi; }
    }
    __syncthreads();

    // Confidence mask + write (100, 5): [ymin, xmin, ymax, xmax, score] or zeros.
    if (t < MAXDET) {
        unsigned long long km = (t < 64) ? keepOut[0] : keepOut[1];
        bool kb = (km >> (t & 63)) & 1ull;
        bool k = kb && (ssc[t] >= 0.75f);
        float* o = out + t * 5;
        o[0] = k ? bx[t][0] : 0.0f;
        o[1] = k ? bx[t][1] : 0.0f;
        o[2] = k ? bx[t][2] : 0.0f;
        o[3] = k ? bx[t][3] : 0.0f;
        o[4] = k ? ssc[t]   : 0.0f;
    }
}

extern "C" void kernel_launch(void* const* d_in, const int* in_sizes, int n_in,
                              void* d_out, int out_size, void* d_ws, size_t ws_size,
                              hipStream_t stream) {
    const float* raw_boxes  = (const float*)d_in[0];   // (1, N, 16)
    const float* raw_scores = (const float*)d_in[1];   // (1, N, 1)
    const float* anchors    = (const float*)d_in[2];   // (N, 4)
    float* out = (float*)d_out;                        // (100, 5)

    int n_scores = in_sizes[1];
    int n4 = n_scores / 4;

    // Workspace layout (bytes):
    //   [0, 4)          unsigned counter
    //   [16, 16400)     float    cand_score[CAP]
    //   [16400, 32784)  unsigned cand_idx[CAP]
    unsigned* counter = (unsigned*)d_ws;
    float*    cs      = (float*)((char*)d_ws + 16);
    unsigned* ci      = (unsigned*)((char*)d_ws + 16400);

    hipMemsetAsync(counter, 0, 4, stream);

    k_compact_static<<<1024, NTHR, 0, stream>>>((const float4*)raw_scores, n4,
                                                counter, cs, ci);
    k_finalize<<<1, NTHR, 0, stream>>>(raw_boxes, anchors,
                                       (const float4*)raw_scores, n4,
                                       cs, ci, counter, out);
}

// Round 3
// 357.550 us; speedup vs baseline: 1.0966x; 1.0966x over previous
//
#include <hip/hip_runtime.h>
#include <math.h>

#define HBINS  4096
#define CAP    4096
#define MAXDET 100
#define NTHR   256
#define NB     1024      // compact grid blocks
#define BPT    (NB / NTHR)   // blocks per finalize-thread (4)
#define BCAP   64        // per-block candidate cap (E[cand/block] ~ 0.2)
// Static prefilter threshold on raw scores. For the benched input
// (4.19M iid N(0,1)): E[count raw>3.9] ~ 202 (sigma ~14) -> n in [100, CAP]
// essentially surely; the exact single-block fallback below covers any other
// input (correct for arbitrary data, just slower).
#define RAW_T0 3.9f

// Order-preserving float -> uint key (larger float => larger key).
static __device__ __forceinline__ unsigned f2key(float f) {
    unsigned u = __float_as_uint(f);
    return (u & 0x80000000u) ? ~u : (u | 0x80000000u);
}

// Composite key: (score key << 32) | (~idx) => max = best score, tie: lowest
// idx. Encodes jax.lax.top_k ordering exactly.
static __device__ __forceinline__ unsigned long long packcand(float s, unsigned idx) {
    return ((unsigned long long)f2key(s) << 32) |
           (unsigned long long)(0xFFFFFFFFu - idx);
}

// Pass 1: each block compacts its candidates (raw > RAW_T0) into a private
// slot. No global atomics; counts written unconditionally so no memset of
// poisoned workspace is needed.
__global__ __launch_bounds__(NTHR) void k_compact(
    const float4* __restrict__ s4, int n4,
    unsigned* __restrict__ counts,
    unsigned long long* __restrict__ cand) {
    __shared__ unsigned lcnt;
    __shared__ unsigned long long lbuf[BCAP];
    if (threadIdx.x == 0) lcnt = 0u;
    __syncthreads();
    int stride = gridDim.x * NTHR;
    for (int i = blockIdx.x * NTHR + threadIdx.x; i < n4; i += stride) {
        float4 v = s4[i];
        float f[4] = {v.x, v.y, v.z, v.w};
#pragma unroll
        for (int c = 0; c < 4; ++c) {
            if (f[c] > RAW_T0) {
                unsigned p = atomicAdd(&lcnt, 1u);
                if (p < BCAP) lbuf[p] = packcand(f[c], (unsigned)(i * 4 + c));
            }
        }
    }
    __syncthreads();
    unsigned c = lcnt;
    unsigned m = c < BCAP ? c : BCAP;
    for (unsigned j = threadIdx.x; j < m; j += NTHR)
        cand[(size_t)blockIdx.x * BCAP + j] = lbuf[j];
    if (threadIdx.x == 0) counts[blockIdx.x] = c;   // raw count (>BCAP => fallback)
}

// Pass 2 (single block): gather candidates, bitonic top-100, decode boxes,
// bitmask greedy NMS, conf filter, write (100,5). Exact fallback
// (histogram + threshold + recompact) for pathological inputs.
__global__ __launch_bounds__(NTHR) void k_finalize(
    const float* __restrict__ rb, const float* __restrict__ an,
    const float4* __restrict__ s4, int n4,
    const unsigned* __restrict__ counts,
    const unsigned long long* __restrict__ cand,
    float* __restrict__ out) {
    __shared__ unsigned long long comp[CAP];   // 32 KB; aliased as hist in fallback
    __shared__ unsigned buf0[NTHR], buf1[NTHR];
    __shared__ unsigned s_tk, s_cnt;
    __shared__ int s_bad;
    __shared__ float bx[MAXDET][4];
    __shared__ float ssc[MAXDET];
    __shared__ unsigned long long suppLo[MAXDET];
    __shared__ unsigned long long suppHi[MAXDET];
    __shared__ unsigned long long keepOut[2];

    int t = threadIdx.x;
    if (t == 0) s_bad = 0;
    __syncthreads();

    // Load my 4 block counts; forward inclusive scan for gather offsets.
    unsigned mycnt[BPT];
    unsigned s = 0;
#pragma unroll
    for (int k = 0; k < BPT; ++k) {
        unsigned c = counts[t * BPT + k];
        if (c > BCAP) s_bad = 1;
        mycnt[k] = c;
        s += c;
    }
    buf0[t] = s;
    __syncthreads();
    unsigned* src = buf0; unsigned* dst = buf1;
    for (int off = 1; off < NTHR; off <<= 1) {     // inclusive forward scan
        unsigned v = src[t];
        if (t >= off) v += src[t - off];
        __syncthreads();
        dst[t] = v;
        __syncthreads();
        unsigned* tmp = src; src = dst; dst = tmp;
    }
    unsigned total = src[NTHR - 1];
    unsigned excl = src[t] - s;
    __syncthreads();

    bool fb = (total < MAXDET) || (total > CAP) || (s_bad != 0);
    unsigned n;
    if (!fb) {
        // Gather my blocks' candidates into comp at scanned offsets.
        unsigned off = excl;
#pragma unroll
        for (int k = 0; k < BPT; ++k) {
            unsigned blk = (unsigned)(t * BPT + k);
            unsigned c = mycnt[k];
            for (unsigned j = 0; j < c; ++j)
                comp[off + j] = cand[(size_t)blk * BCAP + j];
            off += c;
        }
        n = total;
    } else {
        // ---- Exact fallback: single-block histogram -> suffix-scan
        // threshold -> recompact into comp. ----
        unsigned* h = (unsigned*)comp;             // 16 KB alias
        for (int i = t; i < HBINS; i += NTHR) h[i] = 0u;
        __syncthreads();
        for (int i = t; i < n4; i += NTHR) {
            float4 v = s4[i];
            atomicAdd(&h[f2key(v.x) >> 20], 1u);
            atomicAdd(&h[f2key(v.y) >> 20], 1u);
            atomicAdd(&h[f2key(v.z) >> 20], 1u);
            atomicAdd(&h[f2key(v.w) >> 20], 1u);
        }
        __syncthreads();
        unsigned loc[16];
        unsigned ss = 0;
#pragma unroll
        for (int i = 0; i < 16; ++i) { loc[i] = h[t * 16 + i]; ss += loc[i]; }
        buf0[t] = ss;
        __syncthreads();
        unsigned* fsrc = buf0; unsigned* fdst = buf1;
        for (int off = 1; off < NTHR; off <<= 1) { // inclusive suffix scan
            unsigned v = fsrc[t];
            if (t + off < NTHR) v += fsrc[t + off];
            __syncthreads();
            fdst[t] = v;
            __syncthreads();
            unsigned* tmp = fsrc; fsrc = fdst; fdst = tmp;
        }
        unsigned after = (t + 1 < NTHR) ? fsrc[t + 1] : 0u;
        if (after < MAXDET && after + ss >= MAXDET) {
            unsigned run = after;
#pragma unroll
            for (int i = 15; i >= 0; --i) {
                run += loc[i];
                if (run >= MAXDET) { s_tk = ((unsigned)(t * 16 + i)) << 20; break; }
            }
        }
        if (t == 0 && fsrc[0] < MAXDET) s_tk = 0u;  // fewer than 100 total
        if (t == 0) s_cnt = 0u;
        __syncthreads();
        unsigned tk = s_tk;                         // h region dead from here
        for (int i = t; i < n4; i += NTHR) {
            float4 v = s4[i];
            float f[4] = {v.x, v.y, v.z, v.w};
#pragma unroll
            for (int c = 0; c < 4; ++c) {
                if (f2key(f[c]) >= tk) {
                    unsigned p = atomicAdd(&s_cnt, 1u);
                    if (p < CAP) comp[p] = packcand(f[c], (unsigned)(i * 4 + c));
                }
            }
        }
        __syncthreads();
        n = s_cnt < CAP ? s_cnt : CAP;
    }
    __syncthreads();

    // Pad to power of two with 0 (sorts to the tail).
    unsigned P = 128;
    while (P < n) P <<= 1;
    for (unsigned i = n + (unsigned)t; i < P; i += NTHR) comp[i] = 0ull;
    __syncthreads();

    // Bitonic sort, descending. Typical n~200 -> P=256, 36 passes.
    for (unsigned k = 2; k <= P; k <<= 1) {
        for (unsigned j = k >> 1; j > 0; j >>= 1) {
            for (unsigned i = (unsigned)t; i < P; i += NTHR) {
                unsigned l = i ^ j;
                if (l > i) {
                    unsigned long long a = comp[i], b = comp[l];
                    bool up = ((i & k) == 0);          // descending network
                    if (up ? (a < b) : (a > b)) { comp[i] = b; comp[l] = a; }
                }
            }
            __syncthreads();
        }
    }

    // Decode the 100 selected boxes (reference math, fp32) + init supp masks.
    if (t < MAXDET) {
        unsigned long long gb = comp[t];
        float raw;
        unsigned id;
        if (gb == 0ull) {                 // fewer than 100 candidates (pathological)
            raw = -3.0e38f;
            id = 0u;
        } else {
            unsigned key = (unsigned)(gb >> 32);
            unsigned u = (key & 0x80000000u) ? (key & 0x7FFFFFFFu) : ~key;
            raw = __uint_as_float(u);
            id = 0xFFFFFFFFu - (unsigned)(gb & 0xFFFFFFFFull);
        }
        float4 rbv = ((const float4*)rb)[(size_t)id * 4];   // raw_boxes[id][0..3]
        float4 av  = ((const float4*)an)[id];               // anchors[id]
        const float inv = 1.0f / 128.0f;   // INPUT_SIZE, exact power of two
        float xc = rbv.x * inv * av.z + av.x;
        float yc = rbv.y * inv * av.w + av.y;
        float w  = rbv.z * inv * av.z;
        float h  = rbv.w * inv * av.w;
        float y0 = yc - h * 0.5f, y1 = yc + h * 0.5f;
        float x0 = xc - w * 0.5f, x1 = xc + w * 0.5f;
        bx[t][0] = fminf(y0, y1);
        bx[t][1] = fminf(x0, x1);
        bx[t][2] = fmaxf(y0, y1);
        bx[t][3] = fmaxf(x0, x1);
        float r = fminf(fmaxf(raw, -100.0f), 100.0f);
        ssc[t] = 1.0f / (1.0f + expf(-r));
        suppLo[t] = 0ull;
        suppHi[t] = 0ull;
    }
    __syncthreads();

    // Parallel IoU: all (i,j) j>i pairs -> suppression bitmasks (bit j of supp[i]).
    for (int p = t; p < MAXDET * MAXDET; p += NTHR) {
        int i = p / MAXDET, j = p - i * MAXDET;
        if (j > i) {
            float x1i = bx[i][1], y1i = bx[i][0], x2i = bx[i][3], y2i = bx[i][2];
            float x1j = bx[j][1], y1j = bx[j][0], x2j = bx[j][3], y2j = bx[j][2];
            float areai = (x2i - x1i) * (y2i - y1i);
            float areaj = (x2j - x1j) * (y2j - y1j);
            float xx1 = fmaxf(x1i, x1j), yy1 = fmaxf(y1i, y1j);
            float xx2 = fminf(x2i, x2j), yy2 = fminf(y2i, y2j);
            float iw = fmaxf(xx2 - xx1, 0.0f), ih = fmaxf(yy2 - yy1, 0.0f);
            float inter = iw * ih;
            float uni = areai + areaj - inter;
            float iou = inter / fmaxf(uni, 1e-9f);
            if (iou > 0.3f) {
                if (j < 64) atomicOr(&suppLo[i], 1ull << j);
                else        atomicOr(&suppHi[i], 1ull << (j - 64));
            }
        }
    }
    __syncthreads();

    // Sequential greedy resolve on register-resident masks (wave 0, lockstep).
    // Exactly the reference fori_loop: supp applied only if i still kept at time i.
    if (t < 64) {
        unsigned long long a0 = suppLo[t], a1 = suppHi[t];
        unsigned long long b0 = (t < MAXDET - 64) ? suppLo[64 + t] : 0ull;
        unsigned long long b1 = (t < MAXDET - 64) ? suppHi[64 + t] : 0ull;
        unsigned long long kLo = ~0ull;
        unsigned long long kHi = (1ull << (MAXDET - 64)) - 1;
        for (int i = 0; i < MAXDET - 1; ++i) {
            bool kept = (i < 64) ? ((kLo >> i) & 1ull) : ((kHi >> (i - 64)) & 1ull);
            if (kept) {                                  // uniform across lanes
                unsigned long long mLo = (i < 64) ? __shfl(a0, i) : __shfl(b0, i - 64);
                unsigned long long mHi = (i < 64) ? __shfl(a1, i) : __shfl(b1, i - 64);
                kLo &= ~mLo;
                kHi &= ~mHi;
            }
        }
        if (t == 0) { keepOut[0] = kLo; keepOut[1] = kHi; }
    }
    __syncthreads();

    // Confidence mask + write (100, 5): [ymin, xmin, ymax, xmax, score] or zeros.
    if (t < MAXDET) {
        unsigned long long km = (t < 64) ? keepOut[0] : keepOut[1];
        bool kb = (km >> (t & 63)) & 1ull;
        bool k = kb && (ssc[t] >= 0.75f);
        float* o = out + t * 5;
        o[0] = k ? bx[t][0] : 0.0f;
        o[1] = k ? bx[t][1] : 0.0f;
        o[2] = k ? bx[t][2] : 0.0f;
        o[3] = k ? bx[t][3] : 0.0f;
        o[4] = k ? ssc[t]   : 0.0f;
    }
}

extern "C" void kernel_launch(void* const* d_in, const int* in_sizes, int n_in,
                              void* d_out, int out_size, void* d_ws, size_t ws_size,
                              hipStream_t stream) {
    const float* raw_boxes  = (const float*)d_in[0];   // (1, N, 16)
    const float* raw_scores = (const float*)d_in[1];   // (1, N, 1)
    const float* anchors    = (const float*)d_in[2];   // (N, 4)
    float* out = (float*)d_out;                        // (100, 5)

    int n_scores = in_sizes[1];
    int n4 = n_scores / 4;

    // Workspace layout (bytes) — every word written before read, no memset:
    //   [0, 4096)           unsigned counts[NB]
    //   [4096, 4096+512K)   u64 cand[NB][BCAP]
    unsigned* counts          = (unsigned*)d_ws;
    unsigned long long* cand  = (unsigned long long*)((char*)d_ws + 4096);

    k_compact<<<NB, NTHR, 0, stream>>>((const float4*)raw_scores, n4, counts, cand);
    k_finalize<<<1, NTHR, 0, stream>>>(raw_boxes, anchors,
                                       (const float4*)raw_scores, n4,
                                       counts, cand, out);
}